// Round 1
// baseline (791.809 us; speedup 1.0000x reference)
//
#include <hip/hip_runtime.h>
#include <cstdint>
#include <cstddef>

#define NN 100000
#define NE 1600000
#define D_IN 128
#define D_OUT 64

// ---------------- CSR build ----------------
__global__ void count_deg(const int* __restrict__ dst, int* __restrict__ deg, int E) {
    int e = blockIdx.x * blockDim.x + threadIdx.x;
    if (e < E) atomicAdd(&deg[dst[e]], 1);
}

// pass 1: per-1024-chunk inclusive scan, emit block sums
__global__ void scan1(const int* __restrict__ deg, int* __restrict__ partial,
                      int* __restrict__ bsums, int n) {
    __shared__ int s[1024];
    int tid = threadIdx.x;
    int idx = blockIdx.x * 1024 + tid;
    s[tid] = (idx < n) ? deg[idx] : 0;
    __syncthreads();
    for (int off = 1; off < 1024; off <<= 1) {
        int t = (tid >= off) ? s[tid - off] : 0;
        __syncthreads();
        s[tid] += t;
        __syncthreads();
    }
    if (idx < n) partial[idx] = s[tid];
    if (tid == 1023) bsums[blockIdx.x] = s[tid];
}

// pass 2: scan the (<=128) block sums in one block
__global__ void scan2(int* bsums, int nb) {
    __shared__ int s[128];
    int tid = threadIdx.x;
    s[tid] = (tid < nb) ? bsums[tid] : 0;
    __syncthreads();
    for (int off = 1; off < 128; off <<= 1) {
        int t = (tid >= off) ? s[tid - off] : 0;
        __syncthreads();
        s[tid] += t;
        __syncthreads();
    }
    if (tid < nb) bsums[tid] = s[tid];
}

// pass 3: add offsets, produce rowstart[0..n] (rowstart[0]=0, rowstart[i+1]=incl[i])
__global__ void scan3(const int* __restrict__ partial, const int* __restrict__ bsums,
                      int* __restrict__ rowstart, int n) {
    int idx = blockIdx.x * blockDim.x + threadIdx.x;
    if (idx >= n) return;
    int b = idx >> 10;
    int off = (b > 0) ? bsums[b - 1] : 0;
    rowstart[idx + 1] = partial[idx] + off;
    if (idx == 0) rowstart[0] = 0;
}

__global__ void fill_csr(const int* __restrict__ src, const int* __restrict__ dst,
                         const float* __restrict__ w, int* __restrict__ cursor,
                         int* __restrict__ esrc, float* __restrict__ ew, int E) {
    int e = blockIdx.x * blockDim.x + threadIdx.x;
    if (e >= E) return;
    int d = dst[e];
    int pos = atomicAdd(&cursor[d], 1);
    esrc[pos] = src[e];
    ew[pos]   = w[e];
}

// ---------------- propagation: one wave per dst node ----------------
// Half-wave (32 lanes x float4 = full 128-float row) per edge, 2 edges in flight.
__global__ void __launch_bounds__(256) prop(
        const float* __restrict__ xin, float* __restrict__ xout,
        const int* __restrict__ rowstart, const int* __restrict__ esrc,
        const float* __restrict__ ew, int n) {
    int wid = (blockIdx.x * blockDim.x + threadIdx.x) >> 6;
    if (wid >= n) return;
    int lane = threadIdx.x & 63;
    int half = lane >> 5;
    int l    = lane & 31;
    int beg = rowstart[wid];
    int end = rowstart[wid + 1];
    float4 acc = make_float4(0.f, 0.f, 0.f, 0.f);
    for (int e = beg + half; e < end; e += 2) {
        int   s = esrc[e];
        float w = ew[e];
        float4 v = ((const float4*)(xin + (size_t)s * D_IN))[l];
        acc.x = fmaf(w, v.x, acc.x);
        acc.y = fmaf(w, v.y, acc.y);
        acc.z = fmaf(w, v.z, acc.z);
        acc.w = fmaf(w, v.w, acc.w);
    }
    acc.x += __shfl_xor(acc.x, 32);
    acc.y += __shfl_xor(acc.y, 32);
    acc.z += __shfl_xor(acc.z, 32);
    acc.w += __shfl_xor(acc.w, 32);
    if (half == 0)
        ((float4*)(xout + (size_t)wid * D_IN))[l] = acc;
}

// ---------------- MLP + log_softmax ----------------
// 1024 threads = 8 groups of 128; weights staged in LDS once per block.
#define MLP_NG 8
__global__ void __launch_bounds__(1024) mlp_kernel(
        const float* __restrict__ y, const float* __restrict__ W1,
        const float* __restrict__ b1, const float* __restrict__ W2,
        const float* __restrict__ b2, float* __restrict__ out, int n) {
    __shared__ float sW1[D_IN * D_IN];    // 64 KB, W1[d][k] at d*128+k
    __shared__ float sW2[D_IN * D_OUT];   // 32 KB
    __shared__ float sb1[D_IN];
    __shared__ float sb2[D_OUT];
    __shared__ float srow[MLP_NG][D_IN];
    __shared__ float sh[MLP_NG][D_IN];

    int tid = threadIdx.x;
    for (int i = tid; i < D_IN * D_IN / 4; i += 1024)
        ((float4*)sW1)[i] = ((const float4*)W1)[i];
    for (int i = tid; i < D_IN * D_OUT / 4; i += 1024)
        ((float4*)sW2)[i] = ((const float4*)W2)[i];
    if (tid < D_IN)  sb1[tid] = b1[tid];
    if (tid < D_OUT) sb2[tid] = b2[tid];
    __syncthreads();

    int g = tid >> 7;       // group 0..7
    int t = tid & 127;      // thread within group
    int stride = gridDim.x * MLP_NG;
    int iters = (n + stride - 1) / stride;   // uniform trip count for __syncthreads

    for (int it = 0; it < iters; ++it) {
        int node = it * stride + blockIdx.x * MLP_NG + g;
        bool active = node < n;
        if (active) srow[g][t] = y[(size_t)node * D_IN + t];
        __syncthreads();
        if (active) {
            float acc = sb1[t];
            #pragma unroll
            for (int dq = 0; dq < D_IN / 4; ++dq) {
                float4 r = ((const float4*)srow[g])[dq];   // broadcast b128
                acc = fmaf(r.x, sW1[(dq * 4 + 0) * D_IN + t], acc);
                acc = fmaf(r.y, sW1[(dq * 4 + 1) * D_IN + t], acc);
                acc = fmaf(r.z, sW1[(dq * 4 + 2) * D_IN + t], acc);
                acc = fmaf(r.w, sW1[(dq * 4 + 3) * D_IN + t], acc);
            }
            sh[g][t] = fmaxf(acc, 0.f);
        }
        __syncthreads();
        if (active && t < D_OUT) {
            // threads [g*128, g*128+64) are exactly lanes 0..63 of wave 2g
            float acc = sb2[t];
            #pragma unroll
            for (int kq = 0; kq < D_IN / 4; ++kq) {
                float4 h = ((const float4*)sh[g])[kq];
                acc = fmaf(h.x, sW2[(kq * 4 + 0) * D_OUT + t], acc);
                acc = fmaf(h.y, sW2[(kq * 4 + 1) * D_OUT + t], acc);
                acc = fmaf(h.z, sW2[(kq * 4 + 2) * D_OUT + t], acc);
                acc = fmaf(h.w, sW2[(kq * 4 + 3) * D_OUT + t], acc);
            }
            float m = acc;
            #pragma unroll
            for (int off = 32; off; off >>= 1) m = fmaxf(m, __shfl_xor(m, off));
            float ex = __expf(acc - m);
            float ssum = ex;
            #pragma unroll
            for (int off = 32; off; off >>= 1) ssum += __shfl_xor(ssum, off);
            float lse = m + __logf(ssum);
            out[(size_t)node * D_OUT + t] = acc - lse;
        }
        __syncthreads();
    }
}

extern "C" void kernel_launch(void* const* d_in, const int* in_sizes, int n_in,
                              void* d_out, int out_size, void* d_ws, size_t ws_size,
                              hipStream_t stream) {
    const float* x  = (const float*)d_in[0];
    const int*   ei = (const int*)  d_in[1];
    const float* w  = (const float*)d_in[2];
    // d_in[3] = is_cluster (ignored, non-cluster path)
    const float* W1 = (const float*)d_in[4];
    const float* b1 = (const float*)d_in[5];
    const float* W2 = (const float*)d_in[6];
    const float* b2 = (const float*)d_in[7];
    float* out = (float*)d_out;

    const int n = NN, E = NE;
    const int* src = ei;
    const int* dst = ei + E;

    char* ws = (char*)d_ws;
    size_t off = 0;
    auto alloc = [&](size_t bytes) {
        char* p = ws + off;
        off += (bytes + 15) & ~(size_t)15;
        return p;
    };
    int*   deg      = (int*)  alloc((size_t)n * 4);
    int*   rowstart = (int*)  alloc((size_t)(n + 1) * 4);
    int*   cursor   = (int*)  alloc((size_t)n * 4);       // also scan scratch
    int*   bsums    = (int*)  alloc(128 * 4);
    int*   esrc     = (int*)  alloc((size_t)E * 4);
    float* ewt      = (float*)alloc((size_t)E * 4);
    float* y1       = (float*)alloc((size_t)n * D_IN * 4);
    float* y2       = (float*)alloc((size_t)n * D_IN * 4);

    hipMemsetAsync(deg, 0, (size_t)n * 4, stream);
    count_deg<<<(E + 255) / 256, 256, 0, stream>>>(dst, deg, E);

    int nb = (n + 1023) / 1024;   // 98 <= 128
    scan1<<<nb, 1024, 0, stream>>>(deg, cursor, bsums, n);
    scan2<<<1, 128, 0, stream>>>(bsums, nb);
    scan3<<<(n + 255) / 256, 256, 0, stream>>>(cursor, bsums, rowstart, n);
    hipMemcpyAsync(cursor, rowstart, (size_t)n * 4, hipMemcpyDeviceToDevice, stream);
    fill_csr<<<(E + 255) / 256, 256, 0, stream>>>(src, dst, w, cursor, esrc, ewt, E);

    int pblocks = (n * 64 + 255) / 256;   // one wave per node
    prop<<<pblocks, 256, 0, stream>>>(x,  y1, rowstart, esrc, ewt, n);
    prop<<<pblocks, 256, 0, stream>>>(y1, y2, rowstart, esrc, ewt, n);

    mlp_kernel<<<256, 1024, 0, stream>>>(y2, W1, b1, W2, b2, out, n);
}

// Round 2
// 400.708 us; speedup vs baseline: 1.9760x; 1.9760x over previous
//
#include <hip/hip_runtime.h>
#include <cstdint>
#include <cstddef>

#define NN 100000
#define NE 1600000
#define D_IN 128
#define D_OUT 64

typedef __attribute__((ext_vector_type(8))) short bf16x8;
typedef __attribute__((ext_vector_type(4))) float f32x4;

__device__ __forceinline__ float bflo(unsigned u) {
    union { unsigned u; float f; } x; x.u = u << 16; return x.f;
}
__device__ __forceinline__ float bfhi(unsigned u) {
    union { unsigned u; float f; } x; x.u = u & 0xffff0000u; return x.f;
}
__device__ __forceinline__ unsigned f2b(float f) {
    union { float f; unsigned u; } x; x.f = f;
    unsigned u = x.u + 0x7fffu + ((x.u >> 16) & 1u);   // RNE
    return u >> 16;
}

// ---------------- CSR build (unchanged from R1) ----------------
__global__ void count_deg(const int* __restrict__ dst, int* __restrict__ deg, int E) {
    int e = blockIdx.x * blockDim.x + threadIdx.x;
    if (e < E) atomicAdd(&deg[dst[e]], 1);
}

__global__ void scan1(const int* __restrict__ deg, int* __restrict__ partial,
                      int* __restrict__ bsums, int n) {
    __shared__ int s[1024];
    int tid = threadIdx.x;
    int idx = blockIdx.x * 1024 + tid;
    s[tid] = (idx < n) ? deg[idx] : 0;
    __syncthreads();
    for (int off = 1; off < 1024; off <<= 1) {
        int t = (tid >= off) ? s[tid - off] : 0;
        __syncthreads();
        s[tid] += t;
        __syncthreads();
    }
    if (idx < n) partial[idx] = s[tid];
    if (tid == 1023) bsums[blockIdx.x] = s[tid];
}

__global__ void scan2(int* bsums, int nb) {
    __shared__ int s[128];
    int tid = threadIdx.x;
    s[tid] = (tid < nb) ? bsums[tid] : 0;
    __syncthreads();
    for (int off = 1; off < 128; off <<= 1) {
        int t = (tid >= off) ? s[tid - off] : 0;
        __syncthreads();
        s[tid] += t;
        __syncthreads();
    }
    if (tid < nb) bsums[tid] = s[tid];
}

__global__ void scan3(const int* __restrict__ partial, const int* __restrict__ bsums,
                      int* __restrict__ rowstart, int n) {
    int idx = blockIdx.x * blockDim.x + threadIdx.x;
    if (idx >= n) return;
    int b = idx >> 10;
    int off = (b > 0) ? bsums[b - 1] : 0;
    rowstart[idx + 1] = partial[idx] + off;
    if (idx == 0) rowstart[0] = 0;
}

__global__ void fill_csr(const int* __restrict__ src, const int* __restrict__ dst,
                         const float* __restrict__ w, int* __restrict__ cursor,
                         int* __restrict__ esrc, float* __restrict__ ew, int E) {
    int e = blockIdx.x * blockDim.x + threadIdx.x;
    if (e >= E) return;
    int d = dst[e];
    int pos = atomicAdd(&cursor[d], 1);
    esrc[pos] = src[e];
    ew[pos]   = w[e];
}

// ---------------- fp32 -> bf16 conversion of x ----------------
__global__ void conv_x(const float4* __restrict__ in, uint4* __restrict__ out, int n8) {
    int i = blockIdx.x * blockDim.x + threadIdx.x;
    if (i >= n8) return;
    float4 a = in[(size_t)i * 2], b = in[(size_t)i * 2 + 1];
    uint4 o;
    o.x = f2b(a.x) | (f2b(a.y) << 16);
    o.y = f2b(a.z) | (f2b(a.w) << 16);
    o.z = f2b(b.x) | (f2b(b.y) << 16);
    o.w = f2b(b.z) | (f2b(b.w) << 16);
    out[i] = o;
}

// ---------------- weight prep: transpose -> bf16 -> XOR-swizzled ----------------
// wt[0..32767]     = W1t: byte (ch*256 + k*2) ^ ((ch&7)<<4), ch<128, k<128
// wt[32768..49151] = W2t: same layout, ch<64
__global__ void prep_w(const float* __restrict__ W1, const float* __restrict__ W2,
                       char* __restrict__ wt) {
    int tid = blockIdx.x * blockDim.x + threadIdx.x;
    if (tid < 128 * 32) {
        int ch = tid >> 5, kq = tid & 31;
        unsigned lo = f2b(W1[(kq * 4 + 0) * 128 + ch]) | (f2b(W1[(kq * 4 + 1) * 128 + ch]) << 16);
        unsigned hi = f2b(W1[(kq * 4 + 2) * 128 + ch]) | (f2b(W1[(kq * 4 + 3) * 128 + ch]) << 16);
        int off = (ch * 256 + kq * 8) ^ ((ch & 7) << 4);
        *(uint2*)(wt + off) = make_uint2(lo, hi);
    } else if (tid < 128 * 32 + 64 * 32) {
        int t = tid - 128 * 32;
        int ch = t >> 5, kq = t & 31;
        unsigned lo = f2b(W2[(kq * 4 + 0) * 64 + ch]) | (f2b(W2[(kq * 4 + 1) * 64 + ch]) << 16);
        unsigned hi = f2b(W2[(kq * 4 + 2) * 64 + ch]) | (f2b(W2[(kq * 4 + 3) * 64 + ch]) << 16);
        int off = 32768 + ((ch * 256 + kq * 8) ^ ((ch & 7) << 4));
        *(uint2*)(wt + off) = make_uint2(lo, hi);
    }
}

// ---------------- propagation: one wave per dst node, bf16 rows ----------------
// quarter-wave (16 lanes x uint4 = 256B row) per edge, 4 edges in flight
__global__ void __launch_bounds__(256) prop_b(
        const uint4* __restrict__ xin, uint4* __restrict__ xout,
        const int* __restrict__ rowstart, const int* __restrict__ esrc,
        const float* __restrict__ ew, int n) {
    int wid = (blockIdx.x * 256 + threadIdx.x) >> 6;
    if (wid >= n) return;
    int lane = threadIdx.x & 63;
    int q = lane >> 4, c = lane & 15;
    int beg = rowstart[wid], end = rowstart[wid + 1];
    float acc[8] = {0.f, 0.f, 0.f, 0.f, 0.f, 0.f, 0.f, 0.f};
    for (int e = beg + q; e < end; e += 4) {
        int   s = esrc[e];
        float w = ew[e];
        uint4 v = xin[(size_t)s * 16 + c];
        acc[0] = fmaf(w, bflo(v.x), acc[0]);
        acc[1] = fmaf(w, bfhi(v.x), acc[1]);
        acc[2] = fmaf(w, bflo(v.y), acc[2]);
        acc[3] = fmaf(w, bfhi(v.y), acc[3]);
        acc[4] = fmaf(w, bflo(v.z), acc[4]);
        acc[5] = fmaf(w, bfhi(v.z), acc[5]);
        acc[6] = fmaf(w, bflo(v.w), acc[6]);
        acc[7] = fmaf(w, bfhi(v.w), acc[7]);
    }
    #pragma unroll
    for (int i = 0; i < 8; ++i) {
        acc[i] += __shfl_xor(acc[i], 16);
        acc[i] += __shfl_xor(acc[i], 32);
    }
    if (q == 0) {
        uint4 o;
        o.x = f2b(acc[0]) | (f2b(acc[1]) << 16);
        o.y = f2b(acc[2]) | (f2b(acc[3]) << 16);
        o.z = f2b(acc[4]) | (f2b(acc[5]) << 16);
        o.w = f2b(acc[6]) | (f2b(acc[7]) << 16);
        xout[(size_t)wid * 16 + c] = o;
    }
}

// ---------------- fused MFMA MLP + log_softmax ----------------
// 256 threads = 4 waves, 32 nodes per wave, 128 nodes per block.
// LDS: [0,48K) = W1t+W2t swizzled, [48K, 80K) = per-wave hT[128ch][32node] bf16.
__global__ void __launch_bounds__(256) mlp_mfma(
        const unsigned short* __restrict__ y2b, const char* __restrict__ wt,
        const float* __restrict__ b1, const float* __restrict__ b2,
        float* __restrict__ out, int n) {
    __shared__ char lds[81920];
    int tid = threadIdx.x;
    for (int i = tid; i < 3072; i += 256)
        ((uint4*)lds)[i] = ((const uint4*)wt)[i];
    __syncthreads();

    int wave = tid >> 6, lane = tid & 63;
    int c = lane & 15, g = lane >> 4;
    int nb = blockIdx.x * 128 + wave * 32;
    char* ht = lds + 49152 + wave * 8192;

    // ---- lin1: D1[node][ch] = y2b @ W1 + b1 ----
    f32x4 acc[2][8];
    #pragma unroll
    for (int t = 0; t < 8; ++t) {
        float bv = b1[t * 16 + c];
        f32x4 v = {bv, bv, bv, bv};
        acc[0][t] = v; acc[1][t] = v;
    }
    #pragma unroll
    for (int ks = 0; ks < 4; ++ks) {
        bf16x8 a[2];
        #pragma unroll
        for (int r = 0; r < 2; ++r) {
            int row = nb + r * 16 + c;
            if (row >= n) row = n - 1;
            a[r] = *(const bf16x8*)(y2b + (size_t)row * 128 + ks * 32 + g * 8);
        }
        #pragma unroll
        for (int t = 0; t < 8; ++t) {
            int ch = t * 16 + c;
            int off = (ch * 256 + ks * 64 + g * 16) ^ ((ch & 7) << 4);
            bf16x8 b = *(const bf16x8*)(lds + off);
            acc[0][t] = __builtin_amdgcn_mfma_f32_16x16x32_bf16(a[0], b, acc[0][t], 0, 0, 0);
            acc[1][t] = __builtin_amdgcn_mfma_f32_16x16x32_bf16(a[1], b, acc[1][t], 0, 0, 0);
        }
    }
    // relu + cvt bf16, store hT[ch][node] (rows 64 B), 4 consecutive nodes per write
    #pragma unroll
    for (int r = 0; r < 2; ++r) {
        #pragma unroll
        for (int t = 0; t < 8; ++t) {
            int ch = t * 16 + c;
            unsigned lo = f2b(fmaxf(acc[r][t][0], 0.f)) | (f2b(fmaxf(acc[r][t][1], 0.f)) << 16);
            unsigned hi = f2b(fmaxf(acc[r][t][2], 0.f)) | (f2b(fmaxf(acc[r][t][3], 0.f)) << 16);
            *(uint2*)(ht + ch * 64 + (r * 16 + g * 4) * 2) = make_uint2(lo, hi);
        }
    }
    __syncthreads();

    // ---- lin2 (transposed): G[oc][node] = W2^T @ h^T + b2 ----
    f32x4 g2[4][2];
    #pragma unroll
    for (int T = 0; T < 4; ++T) {
        float4 bb = *(const float4*)(b2 + T * 16 + g * 4);
        f32x4 v = {bb.x, bb.y, bb.z, bb.w};
        g2[T][0] = v; g2[T][1] = v;
    }
    #pragma unroll
    for (int ks = 0; ks < 4; ++ks) {
        bf16x8 aw[4];
        #pragma unroll
        for (int T = 0; T < 4; ++T) {
            int oc = T * 16 + c;
            int off = 32768 + ((oc * 256 + ks * 64 + g * 16) ^ ((oc & 7) << 4));
            aw[T] = *(const bf16x8*)(lds + off);
        }
        bf16x8 hb[2];
        #pragma unroll
        for (int p = 0; p < 2; ++p) {
            #pragma unroll
            for (int j = 0; j < 8; ++j) {
                int k = ks * 32 + g * 8 + j;
                hb[p][j] = *(const short*)(ht + k * 64 + (p * 16 + c) * 2);
            }
        }
        #pragma unroll
        for (int T = 0; T < 4; ++T) {
            #pragma unroll
            for (int p = 0; p < 2; ++p)
                g2[T][p] = __builtin_amdgcn_mfma_f32_16x16x32_bf16(aw[T], hb[p], g2[T][p], 0, 0, 0);
        }
    }

    // ---- log_softmax over oc (16 in-lane values + 2 shuffles) ----
    #pragma unroll
    for (int p = 0; p < 2; ++p) {
        int node = nb + p * 16 + c;
        float m = -1e30f;
        #pragma unroll
        for (int T = 0; T < 4; ++T)
            #pragma unroll
            for (int j = 0; j < 4; ++j) m = fmaxf(m, g2[T][p][j]);
        m = fmaxf(m, __shfl_xor(m, 16));
        m = fmaxf(m, __shfl_xor(m, 32));
        float s = 0.f;
        #pragma unroll
        for (int T = 0; T < 4; ++T)
            #pragma unroll
            for (int j = 0; j < 4; ++j) s += __expf(g2[T][p][j] - m);
        s += __shfl_xor(s, 16);
        s += __shfl_xor(s, 32);
        float lse = m + __logf(s);
        if (node < n) {
            #pragma unroll
            for (int T = 0; T < 4; ++T) {
                float4 o = make_float4(g2[T][p][0] - lse, g2[T][p][1] - lse,
                                       g2[T][p][2] - lse, g2[T][p][3] - lse);
                *(float4*)(out + (size_t)node * 64 + T * 16 + g * 4) = o;
            }
        }
    }
}

extern "C" void kernel_launch(void* const* d_in, const int* in_sizes, int n_in,
                              void* d_out, int out_size, void* d_ws, size_t ws_size,
                              hipStream_t stream) {
    const float* x  = (const float*)d_in[0];
    const int*   ei = (const int*)  d_in[1];
    const float* w  = (const float*)d_in[2];
    const float* W1 = (const float*)d_in[4];
    const float* b1 = (const float*)d_in[5];
    const float* W2 = (const float*)d_in[6];
    const float* b2 = (const float*)d_in[7];
    float* out = (float*)d_out;

    const int n = NN, E = NE;
    const int* src = ei;
    const int* dst = ei + E;

    char* ws = (char*)d_ws;
    size_t off = 0;
    auto alloc = [&](size_t bytes) {
        char* p = ws + off;
        off += (bytes + 15) & ~(size_t)15;
        return p;
    };
    int*   deg      = (int*)  alloc((size_t)n * 4);
    int*   rowstart = (int*)  alloc((size_t)(n + 1) * 4);
    int*   cursor   = (int*)  alloc((size_t)n * 4);
    int*   bsums    = (int*)  alloc(128 * 4);
    int*   esrc     = (int*)  alloc((size_t)E * 4);
    float* ewt      = (float*)alloc((size_t)E * 4);
    uint4* xb       = (uint4*)alloc((size_t)n * D_IN * 2);
    uint4* y1b      = (uint4*)alloc((size_t)n * D_IN * 2);
    uint4* y2b      = (uint4*)alloc((size_t)n * D_IN * 2);
    char*  wt       = (char*) alloc(49152);

    // bf16 conversions + weight prep
    int n8 = n * D_IN / 8;
    conv_x<<<(n8 + 255) / 256, 256, 0, stream>>>((const float4*)x, xb, n8);
    prep_w<<<(6144 + 255) / 256, 256, 0, stream>>>(W1, W2, wt);

    // CSR build
    hipMemsetAsync(deg, 0, (size_t)n * 4, stream);
    count_deg<<<(E + 255) / 256, 256, 0, stream>>>(dst, deg, E);
    int nb = (n + 1023) / 1024;
    scan1<<<nb, 1024, 0, stream>>>(deg, cursor, bsums, n);
    scan2<<<1, 128, 0, stream>>>(bsums, nb);
    scan3<<<(n + 255) / 256, 256, 0, stream>>>(cursor, bsums, rowstart, n);
    hipMemcpyAsync(cursor, rowstart, (size_t)n * 4, hipMemcpyDeviceToDevice, stream);
    fill_csr<<<(E + 255) / 256, 256, 0, stream>>>(src, dst, w, cursor, esrc, ewt, E);

    // 2-hop propagation (bf16 rows, fp32 accum)
    int pblocks = (n * 64 + 255) / 256;
    prop_b<<<pblocks, 256, 0, stream>>>(xb,  y1b, rowstart, esrc, ewt, n);
    prop_b<<<pblocks, 256, 0, stream>>>(y1b, y2b, rowstart, esrc, ewt, n);

    // fused MFMA MLP + log_softmax
    mlp_mfma<<<(n + 127) / 128, 256, 0, stream>>>((const unsigned short*)y2b, wt,
                                                  b1, b2, out, n);
}

// Round 3
// 320.476 us; speedup vs baseline: 2.4707x; 1.2504x over previous
//
#include <hip/hip_runtime.h>
#include <cstdint>
#include <cstddef>

#define NN 100000
#define NE 1600000
#define D_IN 128
#define D_OUT 64
#define NB_BKT 391        // ceil(NN/256) buckets of 256 dst nodes
#define TILE 8192

typedef __attribute__((ext_vector_type(8))) short bf16x8;
typedef __attribute__((ext_vector_type(4))) float f32x4;

__device__ __forceinline__ float bflo(unsigned u) {
    union { unsigned u; float f; } x; x.u = u << 16; return x.f;
}
__device__ __forceinline__ float bfhi(unsigned u) {
    union { unsigned u; float f; } x; x.u = u & 0xffff0000u; return x.f;
}
__device__ __forceinline__ unsigned f2b(float f) {
    union { float f; unsigned u; } x; x.f = f;
    unsigned u = x.u + 0x7fffu + ((x.u >> 16) & 1u);   // RNE
    return u >> 16;
}

// ---------------- degree count + scan (rowstart) ----------------
__global__ void count_deg(const int* __restrict__ dst, int* __restrict__ deg, int E) {
    int e = blockIdx.x * blockDim.x + threadIdx.x;
    if (e < E) atomicAdd(&deg[dst[e]], 1);
}

__global__ void scan1(const int* __restrict__ deg, int* __restrict__ partial,
                      int* __restrict__ bsums, int n) {
    __shared__ int s[1024];
    int tid = threadIdx.x;
    int idx = blockIdx.x * 1024 + tid;
    s[tid] = (idx < n) ? deg[idx] : 0;
    __syncthreads();
    for (int off = 1; off < 1024; off <<= 1) {
        int t = (tid >= off) ? s[tid - off] : 0;
        __syncthreads();
        s[tid] += t;
        __syncthreads();
    }
    if (idx < n) partial[idx] = s[tid];
    if (tid == 1023) bsums[blockIdx.x] = s[tid];
}

__global__ void scan2(int* bsums, int nb) {
    __shared__ int s[128];
    int tid = threadIdx.x;
    s[tid] = (tid < nb) ? bsums[tid] : 0;
    __syncthreads();
    for (int off = 1; off < 128; off <<= 1) {
        int t = (tid >= off) ? s[tid - off] : 0;
        __syncthreads();
        s[tid] += t;
        __syncthreads();
    }
    if (tid < nb) bsums[tid] = s[tid];
}

__global__ void scan3(const int* __restrict__ partial, const int* __restrict__ bsums,
                      int* __restrict__ rowstart, int n) {
    int idx = blockIdx.x * blockDim.x + threadIdx.x;
    if (idx >= n) return;
    int b = idx >> 10;
    int off = (b > 0) ? bsums[b - 1] : 0;
    rowstart[idx + 1] = partial[idx] + off;
    if (idx == 0) rowstart[0] = 0;
}

__global__ void init_gcur(const int* __restrict__ rowstart, int* __restrict__ gcur, int nb) {
    int b = blockIdx.x * blockDim.x + threadIdx.x;
    if (b < nb) gcur[b] = rowstart[b << 8];
}

// ---------------- bucketed CSR fill, pass 1: multisplit into 256-node buckets ----------------
// packs (src | local_dst<<17, w_bits) into int2; writes bucket-contiguous chunks
__global__ void __launch_bounds__(256) fill_p1(
        const int* __restrict__ src, const int* __restrict__ dst,
        const float* __restrict__ w, int* __restrict__ gcur,
        int2* __restrict__ gbuf, int E) {
    __shared__ int cnt[NB_BKT];
    __shared__ int base[NB_BKT];
    int tid = threadIdx.x;
    int t0 = blockIdx.x * TILE;
    int t1 = min(t0 + TILE, E);
    for (int i = tid; i < NB_BKT; i += 256) cnt[i] = 0;
    __syncthreads();
    for (int e = t0 + tid; e < t1; e += 256)
        atomicAdd(&cnt[dst[e] >> 8], 1);
    __syncthreads();
    for (int i = tid; i < NB_BKT; i += 256) {
        int c = cnt[i];
        base[i] = c ? atomicAdd(&gcur[i], c) : 0;
        cnt[i] = 0;
    }
    __syncthreads();
    for (int e = t0 + tid; e < t1; e += 256) {
        int d = dst[e];
        int b = d >> 8;
        int r = atomicAdd(&cnt[b], 1);
        unsigned u = (unsigned)src[e] | ((unsigned)(d & 255) << 17);
        gbuf[base[b] + r] = make_int2((int)u, __float_as_int(w[e]));
    }
}

// ---------------- pass 2: within-bucket ordering to exact CSR position ----------------
__global__ void __launch_bounds__(256) fill_p2(
        const int2* __restrict__ gbuf, const int* __restrict__ rowstart,
        int2* __restrict__ esrcw, int n) {
    __shared__ int cnt[256];
    int tid = threadIdx.x;
    int node0 = blockIdx.x << 8;
    int beg = rowstart[node0];
    int end = rowstart[min(node0 + 256, n)];
    cnt[tid] = 0;
    __syncthreads();
    for (int i = beg + tid; i < end; i += 256) {
        int2 p = gbuf[i];
        unsigned u = (unsigned)p.x;
        int local = (int)(u >> 17);
        int srcv  = (int)(u & 0x1FFFFu);
        int r = atomicAdd(&cnt[local], 1);
        esrcw[rowstart[node0 + local] + r] = make_int2(srcv, p.y);
    }
}

// ---------------- fp32 -> bf16 conversion of x ----------------
__global__ void conv_x(const float4* __restrict__ in, uint4* __restrict__ out, int n8) {
    int i = blockIdx.x * blockDim.x + threadIdx.x;
    if (i >= n8) return;
    float4 a = in[(size_t)i * 2], b = in[(size_t)i * 2 + 1];
    uint4 o;
    o.x = f2b(a.x) | (f2b(a.y) << 16);
    o.y = f2b(a.z) | (f2b(a.w) << 16);
    o.z = f2b(b.x) | (f2b(b.y) << 16);
    o.w = f2b(b.z) | (f2b(b.w) << 16);
    out[i] = o;
}

// ---------------- weight prep: transpose -> bf16 -> XOR-swizzled ----------------
__global__ void prep_w(const float* __restrict__ W1, const float* __restrict__ W2,
                       char* __restrict__ wt) {
    int tid = blockIdx.x * blockDim.x + threadIdx.x;
    if (tid < 128 * 32) {
        int ch = tid >> 5, kq = tid & 31;
        unsigned lo = f2b(W1[(kq * 4 + 0) * 128 + ch]) | (f2b(W1[(kq * 4 + 1) * 128 + ch]) << 16);
        unsigned hi = f2b(W1[(kq * 4 + 2) * 128 + ch]) | (f2b(W1[(kq * 4 + 3) * 128 + ch]) << 16);
        int off = (ch * 256 + kq * 8) ^ ((ch & 7) << 4);
        *(uint2*)(wt + off) = make_uint2(lo, hi);
    } else if (tid < 128 * 32 + 64 * 32) {
        int t = tid - 128 * 32;
        int ch = t >> 5, kq = t & 31;
        unsigned lo = f2b(W2[(kq * 4 + 0) * 64 + ch]) | (f2b(W2[(kq * 4 + 1) * 64 + ch]) << 16);
        unsigned hi = f2b(W2[(kq * 4 + 2) * 64 + ch]) | (f2b(W2[(kq * 4 + 3) * 64 + ch]) << 16);
        int off = 32768 + ((ch * 256 + kq * 8) ^ ((ch & 7) << 4));
        *(uint2*)(wt + off) = make_uint2(lo, hi);
    }
}

// ---------------- propagation: one wave per dst node, bf16 rows ----------------
// quarter-wave (16 lanes x uint4 = 256B row) per edge; 2 edges in flight per quarter
__global__ void __launch_bounds__(256) prop_b(
        const uint4* __restrict__ xin, uint4* __restrict__ xout,
        const int* __restrict__ rowstart, const int2* __restrict__ esrcw, int n) {
    int wid = (blockIdx.x * 256 + threadIdx.x) >> 6;
    if (wid >= n) return;
    int lane = threadIdx.x & 63;
    int q = lane >> 4, c = lane & 15;
    int beg = rowstart[wid], end = rowstart[wid + 1];
    float acc[8] = {0.f, 0.f, 0.f, 0.f, 0.f, 0.f, 0.f, 0.f};
    int e = beg + q;
    for (; e + 4 < end; e += 8) {
        int2 p0 = esrcw[e];
        int2 p1 = esrcw[e + 4];
        uint4 v0 = xin[(size_t)p0.x * 16 + c];
        uint4 v1 = xin[(size_t)p1.x * 16 + c];
        float w0 = __int_as_float(p0.y), w1 = __int_as_float(p1.y);
        acc[0] = fmaf(w0, bflo(v0.x), acc[0]);
        acc[1] = fmaf(w0, bfhi(v0.x), acc[1]);
        acc[2] = fmaf(w0, bflo(v0.y), acc[2]);
        acc[3] = fmaf(w0, bfhi(v0.y), acc[3]);
        acc[4] = fmaf(w0, bflo(v0.z), acc[4]);
        acc[5] = fmaf(w0, bfhi(v0.z), acc[5]);
        acc[6] = fmaf(w0, bflo(v0.w), acc[6]);
        acc[7] = fmaf(w0, bfhi(v0.w), acc[7]);
        acc[0] = fmaf(w1, bflo(v1.x), acc[0]);
        acc[1] = fmaf(w1, bfhi(v1.x), acc[1]);
        acc[2] = fmaf(w1, bflo(v1.y), acc[2]);
        acc[3] = fmaf(w1, bfhi(v1.y), acc[3]);
        acc[4] = fmaf(w1, bflo(v1.z), acc[4]);
        acc[5] = fmaf(w1, bfhi(v1.z), acc[5]);
        acc[6] = fmaf(w1, bflo(v1.w), acc[6]);
        acc[7] = fmaf(w1, bfhi(v1.w), acc[7]);
    }
    if (e < end) {
        int2 p0 = esrcw[e];
        uint4 v0 = xin[(size_t)p0.x * 16 + c];
        float w0 = __int_as_float(p0.y);
        acc[0] = fmaf(w0, bflo(v0.x), acc[0]);
        acc[1] = fmaf(w0, bfhi(v0.x), acc[1]);
        acc[2] = fmaf(w0, bflo(v0.y), acc[2]);
        acc[3] = fmaf(w0, bfhi(v0.y), acc[3]);
        acc[4] = fmaf(w0, bflo(v0.z), acc[4]);
        acc[5] = fmaf(w0, bfhi(v0.z), acc[5]);
        acc[6] = fmaf(w0, bflo(v0.w), acc[6]);
        acc[7] = fmaf(w0, bfhi(v0.w), acc[7]);
    }
    #pragma unroll
    for (int i = 0; i < 8; ++i) {
        acc[i] += __shfl_xor(acc[i], 16);
        acc[i] += __shfl_xor(acc[i], 32);
    }
    if (q == 0) {
        uint4 o;
        o.x = f2b(acc[0]) | (f2b(acc[1]) << 16);
        o.y = f2b(acc[2]) | (f2b(acc[3]) << 16);
        o.z = f2b(acc[4]) | (f2b(acc[5]) << 16);
        o.w = f2b(acc[6]) | (f2b(acc[7]) << 16);
        xout[(size_t)wid * 16 + c] = o;
    }
}

// ---------------- fused MFMA MLP + log_softmax (unchanged from R2) ----------------
__global__ void __launch_bounds__(256) mlp_mfma(
        const unsigned short* __restrict__ y2b, const char* __restrict__ wt,
        const float* __restrict__ b1, const float* __restrict__ b2,
        float* __restrict__ out, int n) {
    __shared__ char lds[81920];
    int tid = threadIdx.x;
    for (int i = tid; i < 3072; i += 256)
        ((uint4*)lds)[i] = ((const uint4*)wt)[i];
    __syncthreads();

    int wave = tid >> 6, lane = tid & 63;
    int c = lane & 15, g = lane >> 4;
    int nb = blockIdx.x * 128 + wave * 32;
    char* ht = lds + 49152 + wave * 8192;

    f32x4 acc[2][8];
    #pragma unroll
    for (int t = 0; t < 8; ++t) {
        float bv = b1[t * 16 + c];
        f32x4 v = {bv, bv, bv, bv};
        acc[0][t] = v; acc[1][t] = v;
    }
    #pragma unroll
    for (int ks = 0; ks < 4; ++ks) {
        bf16x8 a[2];
        #pragma unroll
        for (int r = 0; r < 2; ++r) {
            int row = nb + r * 16 + c;
            if (row >= n) row = n - 1;
            a[r] = *(const bf16x8*)(y2b + (size_t)row * 128 + ks * 32 + g * 8);
        }
        #pragma unroll
        for (int t = 0; t < 8; ++t) {
            int ch = t * 16 + c;
            int off = (ch * 256 + ks * 64 + g * 16) ^ ((ch & 7) << 4);
            bf16x8 b = *(const bf16x8*)(lds + off);
            acc[0][t] = __builtin_amdgcn_mfma_f32_16x16x32_bf16(a[0], b, acc[0][t], 0, 0, 0);
            acc[1][t] = __builtin_amdgcn_mfma_f32_16x16x32_bf16(a[1], b, acc[1][t], 0, 0, 0);
        }
    }
    #pragma unroll
    for (int r = 0; r < 2; ++r) {
        #pragma unroll
        for (int t = 0; t < 8; ++t) {
            int ch = t * 16 + c;
            unsigned lo = f2b(fmaxf(acc[r][t][0], 0.f)) | (f2b(fmaxf(acc[r][t][1], 0.f)) << 16);
            unsigned hi = f2b(fmaxf(acc[r][t][2], 0.f)) | (f2b(fmaxf(acc[r][t][3], 0.f)) << 16);
            *(uint2*)(ht + ch * 64 + (r * 16 + g * 4) * 2) = make_uint2(lo, hi);
        }
    }
    __syncthreads();

    f32x4 g2[4][2];
    #pragma unroll
    for (int T = 0; T < 4; ++T) {
        float4 bb = *(const float4*)(b2 + T * 16 + g * 4);
        f32x4 v = {bb.x, bb.y, bb.z, bb.w};
        g2[T][0] = v; g2[T][1] = v;
    }
    #pragma unroll
    for (int ks = 0; ks < 4; ++ks) {
        bf16x8 aw[4];
        #pragma unroll
        for (int T = 0; T < 4; ++T) {
            int oc = T * 16 + c;
            int off = 32768 + ((oc * 256 + ks * 64 + g * 16) ^ ((oc & 7) << 4));
            aw[T] = *(const bf16x8*)(lds + off);
        }
        bf16x8 hb[2];
        #pragma unroll
        for (int p = 0; p < 2; ++p) {
            #pragma unroll
            for (int j = 0; j < 8; ++j) {
                int k = ks * 32 + g * 8 + j;
                hb[p][j] = *(const short*)(ht + k * 64 + (p * 16 + c) * 2);
            }
        }
        #pragma unroll
        for (int T = 0; T < 4; ++T) {
            #pragma unroll
            for (int p = 0; p < 2; ++p)
                g2[T][p] = __builtin_amdgcn_mfma_f32_16x16x32_bf16(aw[T], hb[p], g2[T][p], 0, 0, 0);
        }
    }

    #pragma unroll
    for (int p = 0; p < 2; ++p) {
        int node = nb + p * 16 + c;
        float m = -1e30f;
        #pragma unroll
        for (int T = 0; T < 4; ++T)
            #pragma unroll
            for (int j = 0; j < 4; ++j) m = fmaxf(m, g2[T][p][j]);
        m = fmaxf(m, __shfl_xor(m, 16));
        m = fmaxf(m, __shfl_xor(m, 32));
        float s = 0.f;
        #pragma unroll
        for (int T = 0; T < 4; ++T)
            #pragma unroll
            for (int j = 0; j < 4; ++j) s += __expf(g2[T][p][j] - m);
        s += __shfl_xor(s, 16);
        s += __shfl_xor(s, 32);
        float lse = m + __logf(s);
        if (node < n) {
            #pragma unroll
            for (int T = 0; T < 4; ++T) {
                float4 o = make_float4(g2[T][p][0] - lse, g2[T][p][1] - lse,
                                       g2[T][p][2] - lse, g2[T][p][3] - lse);
                *(float4*)(out + (size_t)node * 64 + T * 16 + g * 4) = o;
            }
        }
    }
}

extern "C" void kernel_launch(void* const* d_in, const int* in_sizes, int n_in,
                              void* d_out, int out_size, void* d_ws, size_t ws_size,
                              hipStream_t stream) {
    const float* x  = (const float*)d_in[0];
    const int*   ei = (const int*)  d_in[1];
    const float* w  = (const float*)d_in[2];
    const float* W1 = (const float*)d_in[4];
    const float* b1 = (const float*)d_in[5];
    const float* W2 = (const float*)d_in[6];
    const float* b2 = (const float*)d_in[7];
    float* out = (float*)d_out;

    const int n = NN, E = NE;
    const int* src = ei;
    const int* dst = ei + E;

    char* ws = (char*)d_ws;
    size_t off = 0;
    auto alloc = [&](size_t bytes) {
        char* p = ws + off;
        off += (bytes + 15) & ~(size_t)15;
        return p;
    };
    int*   deg      = (int*)  alloc((size_t)n * 4);
    int*   rowstart = (int*)  alloc((size_t)(n + 1) * 4);
    int*   partial  = (int*)  alloc((size_t)n * 4);
    int*   bsums    = (int*)  alloc(128 * 4);
    int*   gcur     = (int*)  alloc((size_t)NB_BKT * 4);
    int2*  esrcw    = (int2*) alloc((size_t)E * 8);
    uint4* xb       = (uint4*)alloc((size_t)n * D_IN * 2);
    uint4* y1b      = (uint4*)alloc((size_t)n * D_IN * 2);
    uint4* y2b      = (uint4*)alloc((size_t)n * D_IN * 2);
    char*  wt       = (char*) alloc(49152);
    int2*  gbuf     = (int2*)y2b;   // bucket temp aliases y2b (free before prop2)

    // bf16 conversion + weight prep
    int n8 = n * D_IN / 8;
    conv_x<<<(n8 + 255) / 256, 256, 0, stream>>>((const float4*)x, xb, n8);
    prep_w<<<(6144 + 255) / 256, 256, 0, stream>>>(W1, W2, wt);

    // rowstart
    hipMemsetAsync(deg, 0, (size_t)n * 4, stream);
    count_deg<<<(E + 255) / 256, 256, 0, stream>>>(dst, deg, E);
    int nb = (n + 1023) / 1024;
    scan1<<<nb, 1024, 0, stream>>>(deg, partial, bsums, n);
    scan2<<<1, 128, 0, stream>>>(bsums, nb);
    scan3<<<(n + 255) / 256, 256, 0, stream>>>(partial, bsums, rowstart, n);

    // bucketed CSR fill
    init_gcur<<<(NB_BKT + 255) / 256, 256, 0, stream>>>(rowstart, gcur, NB_BKT);
    fill_p1<<<(E + TILE - 1) / TILE, 256, 0, stream>>>(src, dst, w, gcur, gbuf, E);
    fill_p2<<<NB_BKT, 256, 0, stream>>>(gbuf, rowstart, esrcw, n);

    // 2-hop propagation (bf16 rows, fp32 accum)
    int pblocks = (n * 64 + 255) / 256;
    prop_b<<<pblocks, 256, 0, stream>>>(xb,  y1b, rowstart, esrcw, n);
    prop_b<<<pblocks, 256, 0, stream>>>(y1b, y2b, rowstart, esrcw, n);

    // fused MFMA MLP + log_softmax
    mlp_mfma<<<(n + 127) / 128, 256, 0, stream>>>((const unsigned short*)y2b, wt,
                                                  b1, b2, out, n);
}

// Round 4
// 263.505 us; speedup vs baseline: 3.0049x; 1.2162x over previous
//
#include <hip/hip_runtime.h>
#include <cstdint>
#include <cstddef>

#define NN 100000
#define NE 1600000
#define D_IN 128
#define D_OUT 64
#define NB_BKT 391        // ceil(NN/256) buckets of 256 dst nodes
#define TILE 8192

typedef __attribute__((ext_vector_type(8))) short bf16x8;
typedef __attribute__((ext_vector_type(4))) float f32x4;

__device__ __forceinline__ float bflo(unsigned u) {
    union { unsigned u; float f; } x; x.u = u << 16; return x.f;
}
__device__ __forceinline__ float bfhi(unsigned u) {
    union { unsigned u; float f; } x; x.u = u & 0xffff0000u; return x.f;
}
__device__ __forceinline__ unsigned f2b(float f) {
    union { float f; unsigned u; } x; x.f = f;
    unsigned u = x.u + 0x7fffu + ((x.u >> 16) & 1u);   // RNE
    return u >> 16;
}

__device__ __forceinline__ void fma8(float* acc, uint4 v, float w) {
    acc[0] = fmaf(w, bflo(v.x), acc[0]);
    acc[1] = fmaf(w, bfhi(v.x), acc[1]);
    acc[2] = fmaf(w, bflo(v.y), acc[2]);
    acc[3] = fmaf(w, bfhi(v.y), acc[3]);
    acc[4] = fmaf(w, bflo(v.z), acc[4]);
    acc[5] = fmaf(w, bfhi(v.z), acc[5]);
    acc[6] = fmaf(w, bflo(v.w), acc[6]);
    acc[7] = fmaf(w, bfhi(v.w), acc[7]);
}

// ---------------- bucket histogram (391 buckets) ----------------
__global__ void __launch_bounds__(256) hist_bkt(
        const int* __restrict__ dst, int* __restrict__ bcnt, int E) {
    __shared__ int h[NB_BKT];
    int tid = threadIdx.x;
    for (int i = tid; i < NB_BKT; i += 256) h[i] = 0;
    __syncthreads();
    int t0 = blockIdx.x * TILE;
    int t1 = min(t0 + TILE, E);
    for (int e = t0 + tid; e < t1; e += 256)
        atomicAdd(&h[dst[e] >> 8], 1);
    __syncthreads();
    for (int i = tid; i < NB_BKT; i += 256)
        if (h[i]) atomicAdd(&bcnt[i], h[i]);
}

// single block: exclusive scan of 391 bucket counts -> bbase (392 entries) + gcur
__global__ void __launch_bounds__(512) scan_bkt(
        const int* __restrict__ bcnt, int* __restrict__ bbase,
        int* __restrict__ gcur, int E) {
    __shared__ int s[512];
    int tid = threadIdx.x;
    int v = (tid < NB_BKT) ? bcnt[tid] : 0;
    s[tid] = v;
    __syncthreads();
    for (int off = 1; off < 512; off <<= 1) {
        int t = (tid >= off) ? s[tid - off] : 0;
        __syncthreads();
        s[tid] += t;
        __syncthreads();
    }
    if (tid < NB_BKT) {
        int ex = s[tid] - v;
        bbase[tid] = ex;
        gcur[tid] = ex;
    }
    if (tid == 0) bbase[NB_BKT] = E;
}

// ---------------- bucketed CSR fill, pass 1: multisplit into 256-node buckets ----------------
__global__ void __launch_bounds__(256) fill_p1(
        const int* __restrict__ src, const int* __restrict__ dst,
        const float* __restrict__ w, int* __restrict__ gcur,
        int2* __restrict__ gbuf, int E) {
    __shared__ int cnt[NB_BKT];
    __shared__ int base[NB_BKT];
    int tid = threadIdx.x;
    int t0 = blockIdx.x * TILE;
    int t1 = min(t0 + TILE, E);
    for (int i = tid; i < NB_BKT; i += 256) cnt[i] = 0;
    __syncthreads();
    for (int e = t0 + tid; e < t1; e += 256)
        atomicAdd(&cnt[dst[e] >> 8], 1);
    __syncthreads();
    for (int i = tid; i < NB_BKT; i += 256) {
        int c = cnt[i];
        base[i] = c ? atomicAdd(&gcur[i], c) : 0;
        cnt[i] = 0;
    }
    __syncthreads();
    for (int e = t0 + tid; e < t1; e += 256) {
        int d = dst[e];
        int b = d >> 8;
        int r = atomicAdd(&cnt[b], 1);
        unsigned u = (unsigned)src[e] | ((unsigned)(d & 255) << 17);
        gbuf[base[b] + r] = make_int2((int)u, __float_as_int(w[e]));
    }
}

// ---------------- pass 2: local degree count + scan -> rowstart, place edges ----------------
__global__ void __launch_bounds__(256) fill_p2(
        const int2* __restrict__ gbuf, const int* __restrict__ bbase,
        int* __restrict__ rowstart, int2* __restrict__ esrcw, int n, int E) {
    __shared__ int cnt[256];
    __shared__ int lofs[256];
    __shared__ int stmp[256];
    int tid = threadIdx.x;
    int node0 = blockIdx.x << 8;
    int beg = bbase[blockIdx.x], end = bbase[blockIdx.x + 1];
    cnt[tid] = 0;
    __syncthreads();
    for (int i = beg + tid; i < end; i += 256)
        atomicAdd(&cnt[(unsigned)gbuf[i].x >> 17], 1);
    __syncthreads();
    int v = cnt[tid];
    stmp[tid] = v;
    __syncthreads();
    for (int off = 1; off < 256; off <<= 1) {
        int t = (tid >= off) ? stmp[tid - off] : 0;
        __syncthreads();
        stmp[tid] += t;
        __syncthreads();
    }
    lofs[tid] = stmp[tid] - v;   // exclusive local offset
    int node = node0 + tid;
    if (node < n) rowstart[node] = beg + lofs[tid];
    if (node == n - 1) rowstart[n] = E;
    cnt[tid] = 0;
    __syncthreads();
    for (int i = beg + tid; i < end; i += 256) {
        int2 p = gbuf[i];
        unsigned u = (unsigned)p.x;
        int local = (int)(u >> 17);
        int r = atomicAdd(&cnt[local], 1);
        esrcw[beg + lofs[local] + r] = make_int2((int)(u & 0x1FFFFu), p.y);
    }
}

// ---------------- fp32 -> bf16 conversion of x ----------------
__global__ void conv_x(const float4* __restrict__ in, uint4* __restrict__ out, int n8) {
    int i = blockIdx.x * blockDim.x + threadIdx.x;
    if (i >= n8) return;
    float4 a = in[(size_t)i * 2], b = in[(size_t)i * 2 + 1];
    uint4 o;
    o.x = f2b(a.x) | (f2b(a.y) << 16);
    o.y = f2b(a.z) | (f2b(a.w) << 16);
    o.z = f2b(b.x) | (f2b(b.y) << 16);
    o.w = f2b(b.z) | (f2b(b.w) << 16);
    out[i] = o;
}

// ---------------- weight prep: transpose -> bf16 -> XOR-swizzled ----------------
__global__ void prep_w(const float* __restrict__ W1, const float* __restrict__ W2,
                       char* __restrict__ wt) {
    int tid = blockIdx.x * blockDim.x + threadIdx.x;
    if (tid < 128 * 32) {
        int ch = tid >> 5, kq = tid & 31;
        unsigned lo = f2b(W1[(kq * 4 + 0) * 128 + ch]) | (f2b(W1[(kq * 4 + 1) * 128 + ch]) << 16);
        unsigned hi = f2b(W1[(kq * 4 + 2) * 128 + ch]) | (f2b(W1[(kq * 4 + 3) * 128 + ch]) << 16);
        int off = (ch * 256 + kq * 8) ^ ((ch & 7) << 4);
        *(uint2*)(wt + off) = make_uint2(lo, hi);
    } else if (tid < 128 * 32 + 64 * 32) {
        int t = tid - 128 * 32;
        int ch = t >> 5, kq = t & 31;
        unsigned lo = f2b(W2[(kq * 4 + 0) * 64 + ch]) | (f2b(W2[(kq * 4 + 1) * 64 + ch]) << 16);
        unsigned hi = f2b(W2[(kq * 4 + 2) * 64 + ch]) | (f2b(W2[(kq * 4 + 3) * 64 + ch]) << 16);
        int off = 32768 + ((ch * 256 + kq * 8) ^ ((ch & 7) << 4));
        *(uint2*)(wt + off) = make_uint2(lo, hi);
    }
}

// ---------------- propagation: one wave per dst node, bf16 rows ----------------
// quarter-wave (16 lanes x uint4 = 256B row) per edge; 4 edges in flight per quarter
__global__ void __launch_bounds__(256) prop_b(
        const uint4* __restrict__ xin, uint4* __restrict__ xout,
        const int* __restrict__ rowstart, const int2* __restrict__ esrcw, int n) {
    int wid = (blockIdx.x * 256 + threadIdx.x) >> 6;
    if (wid >= n) return;
    int lane = threadIdx.x & 63;
    int q = lane >> 4, c = lane & 15;
    int beg = rowstart[wid], end = rowstart[wid + 1];
    float acc[8] = {0.f, 0.f, 0.f, 0.f, 0.f, 0.f, 0.f, 0.f};
    int e = beg + q;
    for (; e + 12 < end; e += 16) {
        int2 p0 = esrcw[e];
        int2 p1 = esrcw[e + 4];
        int2 p2 = esrcw[e + 8];
        int2 p3 = esrcw[e + 12];
        uint4 v0 = xin[(size_t)p0.x * 16 + c];
        uint4 v1 = xin[(size_t)p1.x * 16 + c];
        uint4 v2 = xin[(size_t)p2.x * 16 + c];
        uint4 v3 = xin[(size_t)p3.x * 16 + c];
        fma8(acc, v0, __int_as_float(p0.y));
        fma8(acc, v1, __int_as_float(p1.y));
        fma8(acc, v2, __int_as_float(p2.y));
        fma8(acc, v3, __int_as_float(p3.y));
    }
    if (e + 4 < end) {
        int2 p0 = esrcw[e];
        int2 p1 = esrcw[e + 4];
        uint4 v0 = xin[(size_t)p0.x * 16 + c];
        uint4 v1 = xin[(size_t)p1.x * 16 + c];
        fma8(acc, v0, __int_as_float(p0.y));
        fma8(acc, v1, __int_as_float(p1.y));
        e += 8;
    }
    if (e < end) {
        int2 p0 = esrcw[e];
        uint4 v0 = xin[(size_t)p0.x * 16 + c];
        fma8(acc, v0, __int_as_float(p0.y));
    }
    #pragma unroll
    for (int i = 0; i < 8; ++i) {
        acc[i] += __shfl_xor(acc[i], 16);
        acc[i] += __shfl_xor(acc[i], 32);
    }
    if (q == 0) {
        uint4 o;
        o.x = f2b(acc[0]) | (f2b(acc[1]) << 16);
        o.y = f2b(acc[2]) | (f2b(acc[3]) << 16);
        o.z = f2b(acc[4]) | (f2b(acc[5]) << 16);
        o.w = f2b(acc[6]) | (f2b(acc[7]) << 16);
        xout[(size_t)wid * 16 + c] = o;
    }
}

// ---------------- fused MFMA MLP + log_softmax ----------------
__global__ void __launch_bounds__(256) mlp_mfma(
        const unsigned short* __restrict__ y2b, const char* __restrict__ wt,
        const float* __restrict__ b1, const float* __restrict__ b2,
        float* __restrict__ out, int n) {
    __shared__ char lds[81920];
    int tid = threadIdx.x;
    for (int i = tid; i < 3072; i += 256)
        ((uint4*)lds)[i] = ((const uint4*)wt)[i];
    __syncthreads();

    int wave = tid >> 6, lane = tid & 63;
    int c = lane & 15, g = lane >> 4;
    int nb = blockIdx.x * 128 + wave * 32;
    char* ht = lds + 49152 + wave * 8192;

    f32x4 acc[2][8];
    #pragma unroll
    for (int t = 0; t < 8; ++t) {
        float bv = b1[t * 16 + c];
        f32x4 v = {bv, bv, bv, bv};
        acc[0][t] = v; acc[1][t] = v;
    }
    #pragma unroll
    for (int ks = 0; ks < 4; ++ks) {
        bf16x8 a[2];
        #pragma unroll
        for (int r = 0; r < 2; ++r) {
            int row = nb + r * 16 + c;
            if (row >= n) row = n - 1;
            a[r] = *(const bf16x8*)(y2b + (size_t)row * 128 + ks * 32 + g * 8);
        }
        #pragma unroll
        for (int t = 0; t < 8; ++t) {
            int ch = t * 16 + c;
            int off = (ch * 256 + ks * 64 + g * 16) ^ ((ch & 7) << 4);
            bf16x8 b = *(const bf16x8*)(lds + off);
            acc[0][t] = __builtin_amdgcn_mfma_f32_16x16x32_bf16(a[0], b, acc[0][t], 0, 0, 0);
            acc[1][t] = __builtin_amdgcn_mfma_f32_16x16x32_bf16(a[1], b, acc[1][t], 0, 0, 0);
        }
    }
    #pragma unroll
    for (int r = 0; r < 2; ++r) {
        #pragma unroll
        for (int t = 0; t < 8; ++t) {
            int ch = t * 16 + c;
            unsigned lo = f2b(fmaxf(acc[r][t][0], 0.f)) | (f2b(fmaxf(acc[r][t][1], 0.f)) << 16);
            unsigned hi = f2b(fmaxf(acc[r][t][2], 0.f)) | (f2b(fmaxf(acc[r][t][3], 0.f)) << 16);
            *(uint2*)(ht + ch * 64 + (r * 16 + g * 4) * 2) = make_uint2(lo, hi);
        }
    }
    __syncthreads();

    f32x4 g2[4][2];
    #pragma unroll
    for (int T = 0; T < 4; ++T) {
        float4 bb = *(const float4*)(b2 + T * 16 + g * 4);
        f32x4 v = {bb.x, bb.y, bb.z, bb.w};
        g2[T][0] = v; g2[T][1] = v;
    }
    #pragma unroll
    for (int ks = 0; ks < 4; ++ks) {
        bf16x8 aw[4];
        #pragma unroll
        for (int T = 0; T < 4; ++T) {
            int oc = T * 16 + c;
            int off = 32768 + ((oc * 256 + ks * 64 + g * 16) ^ ((oc & 7) << 4));
            aw[T] = *(const bf16x8*)(lds + off);
        }
        bf16x8 hb[2];
        #pragma unroll
        for (int p = 0; p < 2; ++p) {
            #pragma unroll
            for (int j = 0; j < 8; ++j) {
                int k = ks * 32 + g * 8 + j;
                hb[p][j] = *(const short*)(ht + k * 64 + (p * 16 + c) * 2);
            }
        }
        #pragma unroll
        for (int T = 0; T < 4; ++T) {
            #pragma unroll
            for (int p = 0; p < 2; ++p)
                g2[T][p] = __builtin_amdgcn_mfma_f32_16x16x32_bf16(aw[T], hb[p], g2[T][p], 0, 0, 0);
        }
    }

    #pragma unroll
    for (int p = 0; p < 2; ++p) {
        int node = nb + p * 16 + c;
        float m = -1e30f;
        #pragma unroll
        for (int T = 0; T < 4; ++T)
            #pragma unroll
            for (int j = 0; j < 4; ++j) m = fmaxf(m, g2[T][p][j]);
        m = fmaxf(m, __shfl_xor(m, 16));
        m = fmaxf(m, __shfl_xor(m, 32));
        float s = 0.f;
        #pragma unroll
        for (int T = 0; T < 4; ++T)
            #pragma unroll
            for (int j = 0; j < 4; ++j) s += __expf(g2[T][p][j] - m);
        s += __shfl_xor(s, 16);
        s += __shfl_xor(s, 32);
        float lse = m + __logf(s);
        if (node < n) {
            #pragma unroll
            for (int T = 0; T < 4; ++T) {
                float4 o = make_float4(g2[T][p][0] - lse, g2[T][p][1] - lse,
                                       g2[T][p][2] - lse, g2[T][p][3] - lse);
                *(float4*)(out + (size_t)node * 64 + T * 16 + g * 4) = o;
            }
        }
    }
}

extern "C" void kernel_launch(void* const* d_in, const int* in_sizes, int n_in,
                              void* d_out, int out_size, void* d_ws, size_t ws_size,
                              hipStream_t stream) {
    const float* x  = (const float*)d_in[0];
    const int*   ei = (const int*)  d_in[1];
    const float* w  = (const float*)d_in[2];
    const float* W1 = (const float*)d_in[4];
    const float* b1 = (const float*)d_in[5];
    const float* W2 = (const float*)d_in[6];
    const float* b2 = (const float*)d_in[7];
    float* out = (float*)d_out;

    const int n = NN, E = NE;
    const int* src = ei;
    const int* dst = ei + E;

    char* ws = (char*)d_ws;
    size_t off = 0;
    auto alloc = [&](size_t bytes) {
        char* p = ws + off;
        off += (bytes + 15) & ~(size_t)15;
        return p;
    };
    int*   rowstart = (int*)  alloc((size_t)(n + 1) * 4);
    int*   bcnt     = (int*)  alloc((size_t)NB_BKT * 4);
    int*   bbase    = (int*)  alloc((size_t)(NB_BKT + 1) * 4);
    int*   gcur     = (int*)  alloc((size_t)NB_BKT * 4);
    int2*  esrcw    = (int2*) alloc((size_t)E * 8);
    uint4* xb       = (uint4*)alloc((size_t)n * D_IN * 2);
    uint4* y1b      = (uint4*)alloc((size_t)n * D_IN * 2);
    uint4* y2b      = (uint4*)alloc((size_t)n * D_IN * 2);
    char*  wt       = (char*) alloc(49152);
    int2*  gbuf     = (int2*)y2b;   // bucket temp aliases y2b (free before prop2)

    // bf16 conversion + weight prep
    int n8 = n * D_IN / 8;
    conv_x<<<(n8 + 255) / 256, 256, 0, stream>>>((const float4*)x, xb, n8);
    prep_w<<<(6144 + 255) / 256, 256, 0, stream>>>(W1, W2, wt);

    // bucketed CSR build (no per-node global histogram / scans)
    hipMemsetAsync(bcnt, 0, (size_t)NB_BKT * 4, stream);
    int ntile = (E + TILE - 1) / TILE;
    hist_bkt<<<ntile, 256, 0, stream>>>(dst, bcnt, E);
    scan_bkt<<<1, 512, 0, stream>>>(bcnt, bbase, gcur, E);
    fill_p1<<<ntile, 256, 0, stream>>>(src, dst, w, gcur, gbuf, E);
    fill_p2<<<NB_BKT, 256, 0, stream>>>(gbuf, bbase, rowstart, esrcw, n, E);

    // 2-hop propagation (bf16 rows, fp32 accum)
    int pblocks = (n * 64 + 255) / 256;
    prop_b<<<pblocks, 256, 0, stream>>>(xb,  y1b, rowstart, esrcw, n);
    prop_b<<<pblocks, 256, 0, stream>>>(y1b, y2b, rowstart, esrcw, n);

    // fused MFMA MLP + log_softmax
    mlp_mfma<<<(n + 127) / 128, 256, 0, stream>>>((const unsigned short*)y2b, wt,
                                                  b1, b2, out, n);
}